// Round 16
// baseline (6417.650 us; speedup 1.0000x reference)
//
#include <hip/hip_runtime.h>

#define TT 336
#define BB 256
#define DD 128
#define HH 1024
#define TD 43008     // T*D
#define BBHH 262144  // B*H elements

// B-pack geometry (ushort units)
#define SSU0 20480u     // layer0 wave stream: 10 ks * 4 ni * 512
#define SSU1 32768u     // layer1 wave stream: 16 ks * 4 ni * 512
#define LBU1 5242880u   // layer1 base = 32 ntiles * 8 slots * SSU0

// zt leading-dim (floats). 132: injective + conflict-free (bank=(4*row+col)%32)
#define ZTS 132

typedef __attribute__((ext_vector_type(8))) short short8;
typedef __attribute__((ext_vector_type(8))) unsigned short ushort8;
typedef __attribute__((ext_vector_type(4))) unsigned short ushort4v;
typedef __attribute__((ext_vector_type(4))) float floatx4;

// ---- workspace layout (bytes) ----
// zpad page [0,4096): zpad reads only [0,1024). Barrier lines at +2048,
// per-XCD copy counters at +2560 (all zeroed by init_zero).
#define OFF_ZPAD 0u
#define OFF_BAR  2048u       // [0]=global ctr, +64*(1+xcd)=8 XCD ctr lines
#define OFF_XCPY 2560u       // 4 layer1-XCD copy counters, 64B apart
#define OFF_HC   4096u       // 4 x 512KB per-XCD h1 staging (old c1/c2 space)
#define OFF_H1   2101248u    // 2 bufs x 512 KB bf16 (swizzled)
#define OFF_H2   3149824u
#define OFF_B1P  4198400u    // 16 KB permuted bias
#define OFF_B2P  4214784u
#define OFF_X    4231168u    // 22,020,096
#define OFF_BP   26251264u   // fragment-linear weight pack, 27,262,976
// end = 53,514,240

static __device__ __forceinline__ unsigned short f2bf(float f) {
  unsigned int x = __float_as_uint(f);
  x += 0x7fffu + ((x >> 16) & 1u);   // RNE
  return (unsigned short)(x >> 16);
}
static __device__ __forceinline__ float bf2f(unsigned short u) {
  return __uint_as_float(((unsigned int)u) << 16);
}
static __device__ __forceinline__ float sigm(float x) {
  return 1.f / (1.f + __expf(-x));
}
static __device__ __forceinline__ float tanh_fast(float x) {
  float ax = fabsf(x);
  float e = __expf(-2.f * ax);
  float t = (1.f - e) / (1.f + e);
  return x < 0.f ? -t : t;
}

// plain cached load->LDS (read-only / XCD-local data)
#define GLOAD_LDS16(gsrc, ldst)                                              \
  __builtin_amdgcn_global_load_lds(                                          \
      (const __attribute__((address_space(1))) void*)(gsrc),                 \
      (__attribute__((address_space(3))) void*)(ldst), 16, 0, 0)
// device-coherent load->LDS (aux=17 = sc0|sc1): bypasses L1/L2, reads the
// coherent point. Used for h produced by other XCDs between phases.
#define GLOAD_LDS16_DC(gsrc, ldst)                                           \
  __builtin_amdgcn_global_load_lds(                                          \
      (const __attribute__((address_space(1))) void*)(gsrc),                 \
      (__attribute__((address_space(3))) void*)(ldst), 16, 0, 17)
// L1-bypass, L2-CACHED load->LDS (aux=1 = sc0). Used for the XCD-local h1
// staging buffer: lines are dirty in THIS XCD's L2 (written by sibling
// blocks); sc0 skips the per-CU L1 (which may hold stale lines from the
// previous phase) and hits L2.
#define GLOAD_LDS16_L2(gsrc, ldst)                                           \
  __builtin_amdgcn_global_load_lds(                                          \
      (const __attribute__((address_space(1))) void*)(gsrc),                 \
      (__attribute__((address_space(3))) void*)(ldst), 16, 0, 1)

// pin issue-order / block compiler memory reordering (0 instructions)
#define ASM_MEMBAR asm volatile("" ::: "memory")

// -------- init: zero zpad/bar/ctrs/staging/h bufs [0, OFF_B1P) + d_out ----
__global__ __launch_bounds__(256) void init_zero(float* out, uint4* span, long n16) {
  long i = (long)blockIdx.x * 256 + threadIdx.x;
  if (i < n16) span[i] = make_uint4(0u, 0u, 0u, 0u);
  if (i == 0) out[0] = 0.f;
}

// ------- features fp32 -> bf16, quad-swizzled by batch row ----------------
__global__ __launch_bounds__(256) void feat2bf(const float* __restrict__ in,
                                               unsigned short* __restrict__ out, long nq) {
  long Q = (long)blockIdx.x * 256 + threadIdx.x;
  if (Q >= nq) return;
  int b = (int)(Q / 5376);
  long outQ = (Q & ~7L) | ((Q ^ (long)b) & 7);
  const floatx4* pp = (const floatx4*)(in + Q * 8);
  floatx4 a = pp[0], c = pp[1];
  ushort8 v;
  #pragma unroll
  for (int q = 0; q < 4; ++q) { v[q] = f2bf(a[q]); v[4 + q] = f2bf(c[q]); }
  *(ushort8*)(out + outQ * 8) = v;
}

// ---- pack W (K x 4096 f32) into fragment-linear bf16 ---------------------
__global__ __launch_bounds__(256) void bpack(const float* __restrict__ W1,
                                             const float* __restrict__ W2,
                                             unsigned short* __restrict__ out) {
  __shared__ unsigned short tile[64][72];
  int bid = blockIdx.x, t = threadIdx.x;
  int L, tk, tn;
  if (bid < 1280) { L = 0; tk = bid % 20; tn = bid / 20; }
  else            { L = 1; tk = (bid - 1280) % 32; tn = (bid - 1280) / 32; }
  const float* W = L ? W2 : W1;
  int KG = L ? 512 : 320;
  int k0 = tk * 64, n0p = tn * 64;
  int g = k0 / KG;
  int ksg0 = (k0 - g * KG) >> 5;
  int ntile = n0p >> 7, wn = (n0p >> 6) & 1;
  unsigned int SSu = L ? SSU1 : SSU0;
  unsigned int base = (L ? LBU1 : 0u) + ntile * 8u * SSu + (g * 2 + wn) * SSu;

  #pragma unroll
  for (int i = 0; i < 16; ++i) {
    int idx = i * 256 + t;
    int kk = idx >> 6, nn = idx & 63;
    int np = n0p + nn;
    int norig = ((np & 3) << 10) + (np >> 2);
    float v = 0.f;
    if (!(L == 0 && k0 + kk >= 1152)) v = W[(size_t)(k0 + kk) * 4096 + norig];
    tile[kk][nn] = f2bf(v);
  }
  __syncthreads();
  int t64 = t & 63;
  #pragma unroll
  for (int pass = 0; pass < 2; ++pass) {
    int f = (t >> 6) + pass * 4;
    int ksl = f >> 2, ni = f & 3;
    ushort8 v;
    #pragma unroll
    for (int j = 0; j < 8; ++j)
      v[j] = tile[ksl * 32 + ((t64 >> 4) << 3) + j][ni * 16 + (t64 & 15)];
    *(ushort8*)(out + base + (unsigned)((ksg0 + ksl) * 4 + ni) * 512u + t64 * 8) = v;
  }
}

// ---- permute biases: bp[u*4+g] = b[g*1024+u] -----------------------------
__global__ __launch_bounds__(256) void bias_perm(const float* __restrict__ b1,
                                                 const float* __restrict__ b2,
                                                 float* __restrict__ b1p,
                                                 float* __restrict__ b2p) {
  int idx = blockIdx.x * 256 + threadIdx.x;
  const float* src = (idx < 4096) ? b1 : b2;
  float* dst = (idx < 4096) ? b1p : b2p;
  int n = idx & 4095;
  dst[n] = src[(n & 3) * 1024 + (n >> 2)];
}

// ---------------- persistent fused kernel ---------------------------------
// R16 = R15 + PER-XCD h1 STAGING for layer1 (DC-read once, L2-read 32x).
// Diagnosis: ~50MB/phase of device-coherent (sc0|sc1) reads ~ 3 TB/s at
// the coherent point -- each h slab is DC-re-read by 32 same-mtile blocks
// because DC bypasses L2. Layer1 (critical path) now stages h1 once per
// XCD: after the global barrier, the 32 blocks of each layer1 XCD each
// DC-copy a 16KB slice of the fresh 512KB h1 buffer into an XCD-private
// staging buffer (plain stores -> dirty in own L2; never cross-XCD), post
// a per-XCD monotonic counter, poll to 32*p, then the k-loop's kb<1024
// A-stages read the staging buffer with aux=1 (sc0: L1-bypass, L2-hit).
// h2 reads stay DC; layer0 is unchanged (not the critical path; only 2MB
// of scratch exists). Numerics bit-exact (staging is a pure copy).
// Everything else identical to R15 (layer-partitioned XCDs, ping-pong B,
// pair-flag k-loop, zt overlay, tail-B0, hierarchical barrier).
__global__ __launch_bounds__(512, 2) void lstm_persist(
    const unsigned short* __restrict__ Xbf,
    unsigned short* __restrict__ h1bufs, unsigned short* __restrict__ h2bufs,
    const unsigned short* __restrict__ Bpack,
    const float* __restrict__ b1p, const float* __restrict__ b2p,
    const unsigned short* __restrict__ zpad,
    unsigned int* __restrict__ bar, unsigned int* __restrict__ xcpy,
    unsigned short* __restrict__ hcb) {
  __shared__ __align__(16) unsigned short Abuf[4][3][64 * 64];  // 96 KB
  __shared__ int sflags[4][2];                                  // pair flags
  // zt overlays Abuf (temporally disjoint): 2 x 64*132*4B = 67.6 KB <= 96 KB
  float* zt0 = (float*)&Abuf[0][0][0];
  float* zt1 = zt0 + 64 * ZTS;

  int bid = blockIdx.x;
  // layer-partitioned decode: layer0 -> XCD slots 0-3, layer1 -> 4-7
  int xs = bid & 7;
  int layer = xs >> 2;
  int lid = ((bid >> 3) << 2) | (xs & 3);   // 0..127 within layer
  int ntile = (lid & 7) | (((lid >> 5) & 3) << 3);
  int mtile = (lid >> 3) & 3;
  int m0 = mtile * 64;
  int u0 = ntile * 32;
  const int NIT = layer ? 8 : 5;

  int tid = threadIdx.x;
  int g = tid >> 7;           // k-group 0..3
  int wn = (tid >> 6) & 1;    // wave-in-group (n half)
  int lane = tid & 63;
  int kgbase = g * (layer ? 512 : 320);

  unsigned int SSu = layer ? SSU1 : SSU0;
  const unsigned short* bwave =
      Bpack + (layer ? LBU1 : 0u) + ntile * 8u * SSu + (unsigned)(g * 2 + wn) * SSu;

  // ---- loop-invariant cell geometry; bias + c state in registers ----
  int r = tid >> 3, ug = tid & 7;
  int rgc = m0 + r;
  const float* bp = (layer ? b2p : b1p) + (size_t)(u0 + ug * 4) * 4;
  floatx4 breg[4];
  #pragma unroll
  for (int k = 0; k < 4; ++k) breg[k] = *(const floatx4*)&bp[k * 4];
  floatx4 creg = (floatx4){0.f, 0.f, 0.f, 0.f};

  // hierarchical barrier lines (64 B apart); 32 blocks per line
  unsigned int* gctr = bar;                        // global line
  unsigned int* xctr = bar + 16 * (1 + (bid & 7)); // this block's XCD line

  // layer1 staging: per-XCD buffer + counter + this block's 16KB slice
  unsigned short* hcbuf = hcb + (size_t)(xs & 3) * 262144;   // 512KB each
  unsigned int* xcc = xcpy + 16 * (xs & 3);                  // 64B lines
  int s5 = (bid >> 3) & 31;                                  // slice 0..31

  // init pair flags (monotonic across phases)
  if (tid < 8) sflags[tid >> 1][tid & 1] = 0;
  __syncthreads();

  // two B fragment sets, ping-pong (no copies)
  ushort8 bc[2][4], bn[2][4];
  auto loadB = [&](ushort8 (&dst)[2][4], int it) {
    #pragma unroll
    for (int ksl = 0; ksl < 2; ++ksl)
      #pragma unroll
      for (int ni = 0; ni < 4; ++ni)
        dst[ksl][ni] =
            *(const ushort8*)(bwave + (unsigned)((it * 2 + ksl) * 4 + ni) * 512u + lane * 8);
  };

  // prologue: B0 -> bc, in flight before phase 0
  loadB(bc, 0);
  ASM_MEMBAR;

  for (int p = 0; p <= TT; ++p) {
    bool active = layer ? (p >= 1) : (p < TT);
    if (active) {
      const unsigned short* hp1 = h1bufs + (size_t)(p & 1) * BBHH;
      const unsigned short* hp2 = h2bufs + (size_t)(p & 1) * BBHH;
      int acts = layer ? (p - 1) : p;
      int fbase = acts * NIT;
      volatile int* myf = (volatile int*)&sflags[g][wn];
      volatile int* paf = (volatile int*)&sflags[g][wn ^ 1];

      // ---- layer1: stage fresh h1 once per XCD (DC->regs->local L2) ----
      if (layer == 1) {
        const unsigned long long* csrc =
            (const unsigned long long*)hp1 + (size_t)s5 * 2048 + tid * 4;
        unsigned long long v0 = __hip_atomic_load(csrc + 0, __ATOMIC_RELAXED, __HIP_MEMORY_SCOPE_AGENT);
        unsigned long long v1 = __hip_atomic_load(csrc + 1, __ATOMIC_RELAXED, __HIP_MEMORY_SCOPE_AGENT);
        unsigned long long v2 = __hip_atomic_load(csrc + 2, __ATOMIC_RELAXED, __HIP_MEMORY_SCOPE_AGENT);
        unsigned long long v3 = __hip_atomic_load(csrc + 3, __ATOMIC_RELAXED, __HIP_MEMORY_SCOPE_AGENT);
        unsigned long long* cdst =
            (unsigned long long*)hcbuf + (size_t)s5 * 2048 + tid * 4;
        cdst[0] = v0; cdst[1] = v1; cdst[2] = v2; cdst[3] = v3;
        ASM_MEMBAR;
        asm volatile("s_waitcnt vmcnt(0)" ::: "memory");  // stores in L2
        __builtin_amdgcn_s_barrier();                     // all waves done
        if (tid == 0) {
          __hip_atomic_fetch_add(xcc, 1u, __ATOMIC_RELAXED, __HIP_MEMORY_SCOPE_AGENT);
          unsigned int want = 32u * (unsigned int)p;      // p-th active copy
          while (__hip_atomic_load(xcc, __ATOMIC_RELAXED, __HIP_MEMORY_SCOPE_AGENT) < want)
            __builtin_amdgcn_s_sleep(1);
        }
        __builtin_amdgcn_s_barrier();                     // staging visible
      }

      auto stageA = [&](int buf, int it) {
        int kb = kgbase + (it << 6);
        unsigned short* dst0 = &Abuf[g][buf][0];
        #pragma unroll
        for (int c = 0; c < 4; ++c) {
          int rowbase = c * 16 + wn * 8;          // wave-uniform
          int rg = m0 + rowbase + (lane >> 3);
          int kq = lane & 7;
          if (layer == 0) {
            if (kb < DD) {
              GLOAD_LDS16(Xbf + (size_t)rg * TD + p * DD + kb + kq * 8,
                          dst0 + rowbase * 64);
            } else if (kb < 1152) {
              GLOAD_LDS16_DC(hp1 + (size_t)rg * HH + (kb - DD) + kq * 8,
                             dst0 + rowbase * 64);
            } else {
              GLOAD_LDS16(zpad + lane * 8, dst0 + rowbase * 64);  // zero K-pad
            }
          } else {
            if (kb < HH) {
              // XCD-local staged h1: L1-bypass, L2-hit (dirty local lines)
              GLOAD_LDS16_L2(hcbuf + (size_t)rg * HH + kb + kq * 8,
                             dst0 + rowbase * 64);
            } else {
              GLOAD_LDS16_DC(hp2 + (size_t)rg * HH + (kb - HH) + kq * 8,
                             dst0 + rowbase * 64);
            }
          }
        }
      };

      floatx4 acc[4][4];
      #pragma unroll
      for (int i = 0; i < 4; ++i)
        #pragma unroll
        for (int j = 0; j < 4; ++j) acc[i][j] = (floatx4){0.f, 0.f, 0.f, 0.f};

      auto computeIt = [&](int buf, ushort8 (&bb)[2][4]) {
        const unsigned short* Ab = &Abuf[g][buf][0];
        #pragma unroll
        for (int ksl = 0; ksl < 2; ++ksl) {
          int qb = ksl * 4 + (lane >> 4);
          short8 af[4];
          #pragma unroll
          for (int mi = 0; mi < 4; ++mi) {
            int ml = mi * 16 + (lane & 15);
            af[mi] = *(const short8*)&Ab[ml * 64 + ((qb ^ (ml & 7)) << 3)];
          }
          #pragma unroll
          for (int mi = 0; mi < 4; ++mi)
            #pragma unroll
            for (int ni = 0; ni < 4; ++ni)
              acc[mi][ni] = __builtin_amdgcn_mfma_f32_16x16x32_bf16(
                  af[mi], (short8)bb[ksl][ni], acc[mi][ni], 0, 0, 0);
        }
      };

      // phase head: stage slots 0,1 (B0 already in flight from tail/prol;
      // layer1's copy vmcnt(0) above may have drained it -- data is safe
      // in registers either way).  FIFO: [B0:8][s0:4][s1:4] (layer0) or
      // [s0:4][s1:4] (layer1, drained) -- vmcnt(4) below is conservative
      // for both: it retires at least B(it)+s(it) and keeps s(it+1).
      stageA(0, 0);
      ASM_MEMBAR;
      stageA(1, 1);
      ASM_MEMBAR;

      // ---- k-loop: ping-pong bodies, pair-flag sync, no copies ----
#define KITER(bX, bY, jj)                                                    \
      {                                                                      \
        int j_ = (jj);                                                       \
        if (j_ < NIT - 1) {                                                  \
          asm volatile("s_waitcnt vmcnt(4)" ::: "memory");                   \
        } else {                                                             \
          asm volatile("s_waitcnt vmcnt(0)" ::: "memory");                   \
        }                                                                    \
        if (lane == 0) *myf = fbase + j_ + 1;                                \
        ASM_MEMBAR;                                                          \
        if (j_ + 1 < NIT) { loadB(bY, j_ + 1); ASM_MEMBAR; }                 \
        while (*paf < fbase + j_ + 1) __builtin_amdgcn_s_sleep(1);           \
        ASM_MEMBAR;                                                          \
        if (j_ + 2 < NIT) { stageA((j_ + 2) % 3, j_ + 2); ASM_MEMBAR; }      \
        computeIt(j_ % 3, bX);                                               \
      }

      for (int j = 0; j < NIT; j += 2) {
        KITER(bc, bn, j);
        if (j + 1 < NIT) KITER(bn, bc, j + 1);
      }
#undef KITER

      // ---- overlay fence: all waves' Abuf ds_reads retired before the
      // aliased zt region is overwritten (block re-convergence point).
      asm volatile("s_waitcnt lgkmcnt(0)" ::: "memory");
      __builtin_amdgcn_s_barrier();
      __builtin_amdgcn_sched_barrier(0);

      // ---- 4-partial reduction through zt0 (g0+g2) and zt1 (g1+g3) ----
      float* ztw = (g & 1) ? zt1 : zt0;
      if (g < 2) {
        #pragma unroll
        for (int mi = 0; mi < 4; ++mi)
          #pragma unroll
          for (int ni = 0; ni < 4; ++ni)
            #pragma unroll
            for (int rr = 0; rr < 4; ++rr) {
              int row = mi * 16 + (lane >> 4) * 4 + rr;
              int col = wn * 64 + ni * 16 + (lane & 15);
              ztw[row * ZTS + col] = acc[mi][ni][rr];
            }
      }
      __syncthreads();
      if (g >= 2) {
        #pragma unroll
        for (int mi = 0; mi < 4; ++mi)
          #pragma unroll
          for (int ni = 0; ni < 4; ++ni)
            #pragma unroll
            for (int rr = 0; rr < 4; ++rr) {
              int row = mi * 16 + (lane >> 4) * 4 + rr;
              int col = wn * 64 + ni * 16 + (lane & 15);
              ztw[row * ZTS + col] += acc[mi][ni][rr];
            }
      }
      __syncthreads();

      // ---- cell: 512 thr, each 4 units; c and bias in registers ----
      {
        unsigned short* hn = (layer ? h2bufs : h1bufs) + (size_t)((p + 1) & 1) * BBHH;
        floatx4 cold = creg, cn;
        ushort4v hv;
        #pragma unroll
        for (int k = 0; k < 4; ++k) {
          int cbase = r * ZTS + (ug * 4 + k) * 4;
          floatx4 gt0 = *(const floatx4*)&zt0[cbase];
          floatx4 gt1 = *(const floatx4*)&zt1[cbase];
          floatx4 bb = breg[k];
          float i_ = gt0[0] + gt1[0] + bb[0];
          float j_ = gt0[1] + gt1[1] + bb[1];
          float f_ = gt0[2] + gt1[2] + bb[2] + 1.f;   // FORGET_BIAS
          float o_ = gt0[3] + gt1[3] + bb[3];
          float nc = cold[k] * sigm(f_) + sigm(i_) * tanh_fast(j_);
          cn[k] = nc;
          hv[k] = f2bf(tanh_fast(nc) * sigm(o_));
        }
        creg = cn;
        int q = (u0 >> 3) + (ug >> 1);   // h quad; swizzle keyed by batch row
        union { ushort4v v; unsigned long long u; } cu;
        cu.v = hv;
        unsigned long long* hdst = (unsigned long long*)
            &hn[(size_t)rgc * HH + (((q & ~7) | ((q ^ rgc) & 7)) << 3) + (ug & 1) * 4];
        __hip_atomic_store(hdst, cu.u, __ATOMIC_RELAXED, __HIP_MEMORY_SCOPE_AGENT);
      }
      ASM_MEMBAR;

      // tail: re-load bc (free after last compute for NIT=5 and 8) with
      // next phase's B0; retire ONLY the h-store -> vmcnt(8).
      loadB(bc, 0);
      ASM_MEMBAR;
      asm volatile("s_waitcnt vmcnt(8)" ::: "memory");
    }
    // inactive blocks: bc still holds B0 (prologue/tail), nothing to drain.

    // ---- hierarchical device barrier (raw s_barrier: B0 stays in flight)
    __builtin_amdgcn_s_barrier();   // every wave drained its h-store above
    if (tid == 0) {
      __hip_atomic_fetch_add(xctr, 1u, __ATOMIC_RELAXED, __HIP_MEMORY_SCOPE_AGENT);
      if (bid < 8) {   // one master per counter line: promote to global
        unsigned int wantx = 32u * (unsigned int)(p + 1);
        while (__hip_atomic_load(xctr, __ATOMIC_RELAXED, __HIP_MEMORY_SCOPE_AGENT) < wantx)
          __builtin_amdgcn_s_sleep(1);
        __hip_atomic_fetch_add(gctr, 1u, __ATOMIC_RELAXED, __HIP_MEMORY_SCOPE_AGENT);
      }
      unsigned int want = 8u * (unsigned int)(p + 1);
      while (__hip_atomic_load(gctr, __ATOMIC_RELAXED, __HIP_MEMORY_SCOPE_AGENT) < want)
        __builtin_amdgcn_s_sleep(1);
    }
    __builtin_amdgcn_s_barrier();
    ASM_MEMBAR;
  }
  asm volatile("s_waitcnt vmcnt(0)" ::: "memory");
}

// ---------------- dense head + MSE loss (h2 swizzled) ---------------------
__global__ __launch_bounds__(64) void head_loss(const unsigned short* __restrict__ h2,
                                                const float* __restrict__ Wd,
                                                const float* __restrict__ bd,
                                                const float* __restrict__ labels,
                                                float* __restrict__ out) {
  int b = blockIdx.x;
  int l = threadIdx.x;
  float pacc[24];
  #pragma unroll
  for (int n = 0; n < 24; ++n) pacc[n] = 0.f;
  for (int k = l; k < HH; k += 64) {
    int ksw = (k & ~63) | ((((k >> 3) ^ b) & 7) << 3) | (k & 7);
    float hv = bf2f(h2[(size_t)b * HH + ksw]);
    const float* wr = Wd + (size_t)k * 24;
    #pragma unroll
    for (int n = 0; n < 24; ++n) pacc[n] += hv * wr[n];
  }
  #pragma unroll
  for (int n = 0; n < 24; ++n) {
    float v = pacc[n];
    for (int off = 32; off > 0; off >>= 1) v += __shfl_down(v, off);
    pacc[n] = v;
  }
  if (l == 0) {
    float s = 0.f;
    #pragma unroll
    for (int n = 0; n < 24; ++n) {
      float pred = pacc[n] + bd[n];
      float d = pred - labels[b * 24 + n];
      s += d * d;
    }
    atomicAdd(out, s * (1.0f / 6144.0f));
  }
}

extern "C" void kernel_launch(void* const* d_in, const int* in_sizes, int n_in,
                              void* d_out, int out_size, void* d_ws, size_t ws_size,
                              hipStream_t stream) {
  const float* features = (const float*)d_in[0];
  const float* labels   = (const float*)d_in[1];
  const float* W1 = (const float*)d_in[2];
  const float* b1 = (const float*)d_in[3];
  const float* W2 = (const float*)d_in[4];
  const float* b2 = (const float*)d_in[5];
  const float* Wd = (const float*)d_in[6];
  const float* bd = (const float*)d_in[7];

  char* ws = (char*)d_ws;
  unsigned short* zpad = (unsigned short*)(ws + OFF_ZPAD);
  unsigned int*   bar  = (unsigned int*)(ws + OFF_BAR);
  unsigned int*   xcpy = (unsigned int*)(ws + OFF_XCPY);
  unsigned short* hcb  = (unsigned short*)(ws + OFF_HC);
  unsigned short* h1   = (unsigned short*)(ws + OFF_H1);
  unsigned short* h2   = (unsigned short*)(ws + OFF_H2);
  float*          b1p  = (float*)(ws + OFF_B1P);
  float*          b2p  = (float*)(ws + OFF_B2P);
  unsigned short* Xbf  = (unsigned short*)(ws + OFF_X);
  unsigned short* BP   = (unsigned short*)(ws + OFF_BP);
  float* out = (float*)d_out;

  init_zero<<<1026, 256, 0, stream>>>(out, (uint4*)ws, 262400L);
  feat2bf<<<5376, 256, 0, stream>>>(features, Xbf, 1376256L);
  bpack<<<3328, 256, 0, stream>>>(W1, W2, BP);
  bias_perm<<<32, 256, 0, stream>>>(b1, b2, b1p, b2p);

  // single persistent launch: 337 barrier-separated phases
  lstm_persist<<<256, 512, 0, stream>>>(Xbf, h1, h2, BP, b1p, b2p, zpad,
                                        bar, xcpy, hcb);

  // final h2 is buffer (TT+1)&1 = 1
  head_loss<<<256, 64, 0, stream>>>(h2 + BBHH, Wd, bd, labels, out);
}

// Round 17
// 5514.745 us; speedup vs baseline: 1.1637x; 1.1637x over previous
//
#include <hip/hip_runtime.h>

#define TT 336
#define BB 256
#define DD 128
#define HH 1024
#define TD 43008     // T*D
#define BBHH 262144  // B*H elements

// B-pack geometry (ushort units)
#define SSU0 20480u     // layer0 wave stream: 10 ks * 4 ni * 512
#define SSU1 32768u     // layer1 wave stream: 16 ks * 4 ni * 512
#define LBU1 5242880u   // layer1 base = 32 ntiles * 8 slots * SSU0

// zt leading-dim (floats). 132: injective + conflict-free (bank=(4*row+col)%32)
#define ZTS 132

typedef __attribute__((ext_vector_type(8))) short short8;
typedef __attribute__((ext_vector_type(8))) unsigned short ushort8;
typedef __attribute__((ext_vector_type(4))) unsigned short ushort4v;
typedef __attribute__((ext_vector_type(4))) float floatx4;

// ---- workspace layout (bytes) ----
#define OFF_ZPAD 0u          // 4 KB zero pad (K-padding source)
#define OFF_BAR  4096u       // barrier lines: [0]=global, [16..143]=8 XCD ctrs
#define OFF_H1   2101248u    // 2 bufs x 512 KB bf16 (swizzled)
#define OFF_H2   3149824u
#define OFF_B1P  4198400u    // 16 KB permuted bias
#define OFF_B2P  4214784u
#define OFF_X    4231168u    // 22,020,096
#define OFF_BP   26251264u   // fragment-linear weight pack, 27,262,976
// end = 53,514,240

static __device__ __forceinline__ unsigned short f2bf(float f) {
  unsigned int x = __float_as_uint(f);
  x += 0x7fffu + ((x >> 16) & 1u);   // RNE
  return (unsigned short)(x >> 16);
}
static __device__ __forceinline__ float bf2f(unsigned short u) {
  return __uint_as_float(((unsigned int)u) << 16);
}
static __device__ __forceinline__ float sigm(float x) {
  return 1.f / (1.f + __expf(-x));
}
static __device__ __forceinline__ float tanh_fast(float x) {
  float ax = fabsf(x);
  float e = __expf(-2.f * ax);
  float t = (1.f - e) / (1.f + e);
  return x < 0.f ? -t : t;
}

// plain cached load->LDS (read-only / XCD-local data)
#define GLOAD_LDS16(gsrc, ldst)                                              \
  __builtin_amdgcn_global_load_lds(                                          \
      (const __attribute__((address_space(1))) void*)(gsrc),                 \
      (__attribute__((address_space(3))) void*)(ldst), 16, 0, 0)
// device-coherent load->LDS (aux=17 = sc0|sc1): bypasses L1/L2, reads the
// coherent point. Used for h1/h2 produced by other XCDs between phases.
#define GLOAD_LDS16_DC(gsrc, ldst)                                           \
  __builtin_amdgcn_global_load_lds(                                          \
      (const __attribute__((address_space(1))) void*)(gsrc),                 \
      (__attribute__((address_space(3))) void*)(ldst), 16, 0, 17)

// pin issue-order / block compiler memory reordering (0 instructions)
#define ASM_MEMBAR asm volatile("" ::: "memory")

// -------- init: zero zpad, barrier, h bufs [0, OFF_B1P) + d_out -----------
__global__ __launch_bounds__(256) void init_zero(float* out, uint4* span, long n16) {
  long i = (long)blockIdx.x * 256 + threadIdx.x;
  if (i < n16) span[i] = make_uint4(0u, 0u, 0u, 0u);
  if (i == 0) out[0] = 0.f;
}

// ------- features fp32 -> bf16, quad-swizzled by batch row ----------------
__global__ __launch_bounds__(256) void feat2bf(const float* __restrict__ in,
                                               unsigned short* __restrict__ out, long nq) {
  long Q = (long)blockIdx.x * 256 + threadIdx.x;
  if (Q >= nq) return;
  int b = (int)(Q / 5376);
  long outQ = (Q & ~7L) | ((Q ^ (long)b) & 7);
  const floatx4* pp = (const floatx4*)(in + Q * 8);
  floatx4 a = pp[0], c = pp[1];
  ushort8 v;
  #pragma unroll
  for (int q = 0; q < 4; ++q) { v[q] = f2bf(a[q]); v[4 + q] = f2bf(c[q]); }
  *(ushort8*)(out + outQ * 8) = v;
}

// ---- pack W (K x 4096 f32) into fragment-linear bf16 ---------------------
__global__ __launch_bounds__(256) void bpack(const float* __restrict__ W1,
                                             const float* __restrict__ W2,
                                             unsigned short* __restrict__ out) {
  __shared__ unsigned short tile[64][72];
  int bid = blockIdx.x, t = threadIdx.x;
  int L, tk, tn;
  if (bid < 1280) { L = 0; tk = bid % 20; tn = bid / 20; }
  else            { L = 1; tk = (bid - 1280) % 32; tn = (bid - 1280) / 32; }
  const float* W = L ? W2 : W1;
  int KG = L ? 512 : 320;
  int k0 = tk * 64, n0p = tn * 64;
  int g = k0 / KG;
  int ksg0 = (k0 - g * KG) >> 5;
  int ntile = n0p >> 7, wn = (n0p >> 6) & 1;
  unsigned int SSu = L ? SSU1 : SSU0;
  unsigned int base = (L ? LBU1 : 0u) + ntile * 8u * SSu + (g * 2 + wn) * SSu;

  #pragma unroll
  for (int i = 0; i < 16; ++i) {
    int idx = i * 256 + t;
    int kk = idx >> 6, nn = idx & 63;
    int np = n0p + nn;
    int norig = ((np & 3) << 10) + (np >> 2);
    float v = 0.f;
    if (!(L == 0 && k0 + kk >= 1152)) v = W[(size_t)(k0 + kk) * 4096 + norig];
    tile[kk][nn] = f2bf(v);
  }
  __syncthreads();
  int t64 = t & 63;
  #pragma unroll
  for (int pass = 0; pass < 2; ++pass) {
    int f = (t >> 6) + pass * 4;
    int ksl = f >> 2, ni = f & 3;
    ushort8 v;
    #pragma unroll
    for (int j = 0; j < 8; ++j)
      v[j] = tile[ksl * 32 + ((t64 >> 4) << 3) + j][ni * 16 + (t64 & 15)];
    *(ushort8*)(out + base + (unsigned)((ksg0 + ksl) * 4 + ni) * 512u + t64 * 8) = v;
  }
}

// ---- permute biases: bp[u*4+g] = b[g*1024+u] -----------------------------
__global__ __launch_bounds__(256) void bias_perm(const float* __restrict__ b1,
                                                 const float* __restrict__ b2,
                                                 float* __restrict__ b1p,
                                                 float* __restrict__ b2p) {
  int idx = blockIdx.x * 256 + threadIdx.x;
  const float* src = (idx < 4096) ? b1 : b2;
  float* dst = (idx < 4096) ? b1p : b2p;
  int n = idx & 4095;
  dst[n] = src[(n & 3) * 1024 + (n >> 2)];
}

// ---------------- persistent fused kernel ---------------------------------
// R17 = R15 verbatim (session best, 5633 us): layer-partitioned XCDs +
// ping-pong B sets + pair-flag k-loop + zt-overlay + tail-B0.
// Tested-and-rejected directions (each with counter-verified mechanism):
//  - deeper B pipeline (R13): L2-sharing desync, FETCH +55%
//  - 2 blocks/CU (R11): VGPR collapse -> scratch; L2 thrash
//  - per-XCD h1 staging (R16): staging writebacks to HBM (WRITE 347KB->
//    1.04GB) + layer1 L2 footprint 4.7MB > 4MiB -> thrash; also falsified
//    the DC-saturation theory (removing DC bytes didn't speed the k-loop)
// bid decode: xs=bid&7; layer=xs>>2; lid=(bid>>3)*4+(xs&3)
//   -> layer0 on XCD slots 0-3 (2.6MB weight set, L2-resident),
//      layer1 on slots 4-7 (4.19MB, partial retention).
// Coherence: h stores sc0|sc1 write-through; h loads DC aux=17; weights
// stay L2-resident (no wbl2/inv anywhere).
// K-loop: 3-slot Abuf, A dist 2, B dist 1 ping-pong (no copies), per-PAIR
// LDS flag sync (monotonic sflags[g][wn]); FIFO at body-top:
// [s(j):4][B(j):8][s(j+1):4] -> vmcnt(4) retires s(j)+B(j); last body
// vmcnt(0); tail loads next-phase B0 -> bc, vmcnt(8) retires only the
// h-store; raw s_barrier keeps B0 in flight across the spin.
// zt OVERLAY on Abuf (temporally disjoint; lgkm-only fence), stride 132.
__global__ __launch_bounds__(512, 2) void lstm_persist(
    const unsigned short* __restrict__ Xbf,
    unsigned short* __restrict__ h1bufs, unsigned short* __restrict__ h2bufs,
    const unsigned short* __restrict__ Bpack,
    const float* __restrict__ b1p, const float* __restrict__ b2p,
    const unsigned short* __restrict__ zpad,
    unsigned int* __restrict__ bar) {
  __shared__ __align__(16) unsigned short Abuf[4][3][64 * 64];  // 96 KB
  __shared__ int sflags[4][2];                                  // pair flags
  // zt overlays Abuf (temporally disjoint): 2 x 64*132*4B = 67.6 KB <= 96 KB
  float* zt0 = (float*)&Abuf[0][0][0];
  float* zt1 = zt0 + 64 * ZTS;

  int bid = blockIdx.x;
  // layer-partitioned decode: layer0 -> XCD slots 0-3, layer1 -> 4-7
  int xs = bid & 7;
  int layer = xs >> 2;
  int lid = ((bid >> 3) << 2) | (xs & 3);   // 0..127 within layer
  int ntile = (lid & 7) | (((lid >> 5) & 3) << 3);
  int mtile = (lid >> 3) & 3;
  int m0 = mtile * 64;
  int u0 = ntile * 32;
  const int NIT = layer ? 8 : 5;

  int tid = threadIdx.x;
  int g = tid >> 7;           // k-group 0..3
  int wn = (tid >> 6) & 1;    // wave-in-group (n half)
  int lane = tid & 63;
  int kgbase = g * (layer ? 512 : 320);

  unsigned int SSu = layer ? SSU1 : SSU0;
  const unsigned short* bwave =
      Bpack + (layer ? LBU1 : 0u) + ntile * 8u * SSu + (unsigned)(g * 2 + wn) * SSu;

  // ---- loop-invariant cell geometry; bias + c state in registers ----
  int r = tid >> 3, ug = tid & 7;
  int rgc = m0 + r;
  const float* bp = (layer ? b2p : b1p) + (size_t)(u0 + ug * 4) * 4;
  floatx4 breg[4];
  #pragma unroll
  for (int k = 0; k < 4; ++k) breg[k] = *(const floatx4*)&bp[k * 4];
  floatx4 creg = (floatx4){0.f, 0.f, 0.f, 0.f};

  // hierarchical barrier lines (64 B apart); 32 blocks per line
  unsigned int* gctr = bar;                        // global line
  unsigned int* xctr = bar + 16 * (1 + (bid & 7)); // this block's XCD line

  // init pair flags (monotonic across phases)
  if (tid < 8) sflags[tid >> 1][tid & 1] = 0;
  __syncthreads();

  // two B fragment sets, ping-pong (no copies)
  ushort8 bc[2][4], bn[2][4];
  auto loadB = [&](ushort8 (&dst)[2][4], int it) {
    #pragma unroll
    for (int ksl = 0; ksl < 2; ++ksl)
      #pragma unroll
      for (int ni = 0; ni < 4; ++ni)
        dst[ksl][ni] =
            *(const ushort8*)(bwave + (unsigned)((it * 2 + ksl) * 4 + ni) * 512u + lane * 8);
  };

  // prologue: B0 -> bc, in flight before phase 0
  loadB(bc, 0);
  ASM_MEMBAR;

  for (int p = 0; p <= TT; ++p) {
    bool active = layer ? (p >= 1) : (p < TT);
    if (active) {
      const unsigned short* hp1 = h1bufs + (size_t)(p & 1) * BBHH;
      const unsigned short* hp2 = h2bufs + (size_t)(p & 1) * BBHH;
      int acts = layer ? (p - 1) : p;
      int fbase = acts * NIT;
      volatile int* myf = (volatile int*)&sflags[g][wn];
      volatile int* paf = (volatile int*)&sflags[g][wn ^ 1];

      auto stageA = [&](int buf, int it) {
        int kb = kgbase + (it << 6);
        unsigned short* dst0 = &Abuf[g][buf][0];
        #pragma unroll
        for (int c = 0; c < 4; ++c) {
          int rowbase = c * 16 + wn * 8;          // wave-uniform
          int rg = m0 + rowbase + (lane >> 3);
          int kq = lane & 7;
          if (layer == 0) {
            if (kb < DD) {
              GLOAD_LDS16(Xbf + (size_t)rg * TD + p * DD + kb + kq * 8,
                          dst0 + rowbase * 64);
            } else if (kb < 1152) {
              GLOAD_LDS16_DC(hp1 + (size_t)rg * HH + (kb - DD) + kq * 8,
                             dst0 + rowbase * 64);
            } else {
              GLOAD_LDS16(zpad + lane * 8, dst0 + rowbase * 64);  // zero K-pad
            }
          } else {
            if (kb < HH) {
              GLOAD_LDS16_DC(hp1 + (size_t)rg * HH + kb + kq * 8,
                             dst0 + rowbase * 64);
            } else {
              GLOAD_LDS16_DC(hp2 + (size_t)rg * HH + (kb - HH) + kq * 8,
                             dst0 + rowbase * 64);
            }
          }
        }
      };

      floatx4 acc[4][4];
      #pragma unroll
      for (int i = 0; i < 4; ++i)
        #pragma unroll
        for (int j = 0; j < 4; ++j) acc[i][j] = (floatx4){0.f, 0.f, 0.f, 0.f};

      auto computeIt = [&](int buf, ushort8 (&bb)[2][4]) {
        const unsigned short* Ab = &Abuf[g][buf][0];
        #pragma unroll
        for (int ksl = 0; ksl < 2; ++ksl) {
          int qb = ksl * 4 + (lane >> 4);
          short8 af[4];
          #pragma unroll
          for (int mi = 0; mi < 4; ++mi) {
            int ml = mi * 16 + (lane & 15);
            af[mi] = *(const short8*)&Ab[ml * 64 + ((qb ^ (ml & 7)) << 3)];
          }
          #pragma unroll
          for (int mi = 0; mi < 4; ++mi)
            #pragma unroll
            for (int ni = 0; ni < 4; ++ni)
              acc[mi][ni] = __builtin_amdgcn_mfma_f32_16x16x32_bf16(
                  af[mi], (short8)bb[ksl][ni], acc[mi][ni], 0, 0, 0);
        }
      };

      // phase head: stage slots 0,1 (B0 already in flight from tail/prol)
      // FIFO: [B0:8][s0:4][s1:4]
      stageA(0, 0);
      ASM_MEMBAR;
      stageA(1, 1);
      ASM_MEMBAR;

      // ---- k-loop: ping-pong bodies, pair-flag sync, no copies ----
      // body(j): wait vmcnt(4) [retires s(j)+B(j); keeps s(j+1)] (last:
      // vmcnt(0)); post flag; loadB(B(j+1))->other set; poll partner;
      // stageA(s(j+2)); compute set for B(j) from Abuf slot j%3.
#define KITER(bX, bY, jj)                                                    \
      {                                                                      \
        int j_ = (jj);                                                       \
        if (j_ < NIT - 1) {                                                  \
          asm volatile("s_waitcnt vmcnt(4)" ::: "memory");                   \
        } else {                                                             \
          asm volatile("s_waitcnt vmcnt(0)" ::: "memory");                   \
        }                                                                    \
        if (lane == 0) *myf = fbase + j_ + 1;                                \
        ASM_MEMBAR;                                                          \
        if (j_ + 1 < NIT) { loadB(bY, j_ + 1); ASM_MEMBAR; }                 \
        while (*paf < fbase + j_ + 1) __builtin_amdgcn_s_sleep(1);           \
        ASM_MEMBAR;                                                          \
        if (j_ + 2 < NIT) { stageA((j_ + 2) % 3, j_ + 2); ASM_MEMBAR; }      \
        computeIt(j_ % 3, bX);                                               \
      }

      for (int j = 0; j < NIT; j += 2) {
        KITER(bc, bn, j);
        if (j + 1 < NIT) KITER(bn, bc, j + 1);
      }
#undef KITER

      // ---- overlay fence: all waves' Abuf ds_reads retired before the
      // aliased zt region is overwritten (block re-convergence point).
      asm volatile("s_waitcnt lgkmcnt(0)" ::: "memory");
      __builtin_amdgcn_s_barrier();
      __builtin_amdgcn_sched_barrier(0);

      // ---- 4-partial reduction through zt0 (g0+g2) and zt1 (g1+g3) ----
      float* ztw = (g & 1) ? zt1 : zt0;
      if (g < 2) {
        #pragma unroll
        for (int mi = 0; mi < 4; ++mi)
          #pragma unroll
          for (int ni = 0; ni < 4; ++ni)
            #pragma unroll
            for (int rr = 0; rr < 4; ++rr) {
              int row = mi * 16 + (lane >> 4) * 4 + rr;
              int col = wn * 64 + ni * 16 + (lane & 15);
              ztw[row * ZTS + col] = acc[mi][ni][rr];
            }
      }
      __syncthreads();
      if (g >= 2) {
        #pragma unroll
        for (int mi = 0; mi < 4; ++mi)
          #pragma unroll
          for (int ni = 0; ni < 4; ++ni)
            #pragma unroll
            for (int rr = 0; rr < 4; ++rr) {
              int row = mi * 16 + (lane >> 4) * 4 + rr;
              int col = wn * 64 + ni * 16 + (lane & 15);
              ztw[row * ZTS + col] += acc[mi][ni][rr];
            }
      }
      __syncthreads();

      // ---- cell: 512 thr, each 4 units; c and bias in registers ----
      {
        unsigned short* hn = (layer ? h2bufs : h1bufs) + (size_t)((p + 1) & 1) * BBHH;
        floatx4 cold = creg, cn;
        ushort4v hv;
        #pragma unroll
        for (int k = 0; k < 4; ++k) {
          int cbase = r * ZTS + (ug * 4 + k) * 4;
          floatx4 gt0 = *(const floatx4*)&zt0[cbase];
          floatx4 gt1 = *(const floatx4*)&zt1[cbase];
          floatx4 bb = breg[k];
          float i_ = gt0[0] + gt1[0] + bb[0];
          float j_ = gt0[1] + gt1[1] + bb[1];
          float f_ = gt0[2] + gt1[2] + bb[2] + 1.f;   // FORGET_BIAS
          float o_ = gt0[3] + gt1[3] + bb[3];
          float nc = cold[k] * sigm(f_) + sigm(i_) * tanh_fast(j_);
          cn[k] = nc;
          hv[k] = f2bf(tanh_fast(nc) * sigm(o_));
        }
        creg = cn;
        int q = (u0 >> 3) + (ug >> 1);   // h quad; swizzle keyed by batch row
        union { ushort4v v; unsigned long long u; } cu;
        cu.v = hv;
        unsigned long long* hdst = (unsigned long long*)
            &hn[(size_t)rgc * HH + (((q & ~7) | ((q ^ rgc) & 7)) << 3) + (ug & 1) * 4];
        __hip_atomic_store(hdst, cu.u, __ATOMIC_RELAXED, __HIP_MEMORY_SCOPE_AGENT);
      }
      ASM_MEMBAR;

      // tail: re-load bc (free after last compute for NIT=5 and 8) with
      // next phase's B0; retire ONLY the h-store -> vmcnt(8).
      loadB(bc, 0);
      ASM_MEMBAR;
      asm volatile("s_waitcnt vmcnt(8)" ::: "memory");
    }
    // inactive blocks: bc still holds B0 (prologue/tail), nothing to drain.

    // ---- hierarchical device barrier (raw s_barrier: B0 stays in flight)
    __builtin_amdgcn_s_barrier();   // every wave drained its h-store above
    if (tid == 0) {
      __hip_atomic_fetch_add(xctr, 1u, __ATOMIC_RELAXED, __HIP_MEMORY_SCOPE_AGENT);
      if (bid < 8) {   // one master per counter line: promote to global
        unsigned int wantx = 32u * (unsigned int)(p + 1);
        while (__hip_atomic_load(xctr, __ATOMIC_RELAXED, __HIP_MEMORY_SCOPE_AGENT) < wantx)
          __builtin_amdgcn_s_sleep(1);
        __hip_atomic_fetch_add(gctr, 1u, __ATOMIC_RELAXED, __HIP_MEMORY_SCOPE_AGENT);
      }
      unsigned int want = 8u * (unsigned int)(p + 1);
      while (__hip_atomic_load(gctr, __ATOMIC_RELAXED, __HIP_MEMORY_SCOPE_AGENT) < want)
        __builtin_amdgcn_s_sleep(1);
    }
    __builtin_amdgcn_s_barrier();
    ASM_MEMBAR;
  }
  asm volatile("s_waitcnt vmcnt(0)" ::: "memory");
}

// ---------------- dense head + MSE loss (h2 swizzled) ---------------------
__global__ __launch_bounds__(64) void head_loss(const unsigned short* __restrict__ h2,
                                                const float* __restrict__ Wd,
                                                const float* __restrict__ bd,
                                                const float* __restrict__ labels,
                                                float* __restrict__ out) {
  int b = blockIdx.x;
  int l = threadIdx.x;
  float pacc[24];
  #pragma unroll
  for (int n = 0; n < 24; ++n) pacc[n] = 0.f;
  for (int k = l; k < HH; k += 64) {
    int ksw = (k & ~63) | ((((k >> 3) ^ b) & 7) << 3) | (k & 7);
    float hv = bf2f(h2[(size_t)b * HH + ksw]);
    const float* wr = Wd + (size_t)k * 24;
    #pragma unroll
    for (int n = 0; n < 24; ++n) pacc[n] += hv * wr[n];
  }
  #pragma unroll
  for (int n = 0; n < 24; ++n) {
    float v = pacc[n];
    for (int off = 32; off > 0; off >>= 1) v += __shfl_down(v, off);
    pacc[n] = v;
  }
  if (l == 0) {
    float s = 0.f;
    #pragma unroll
    for (int n = 0; n < 24; ++n) {
      float pred = pacc[n] + bd[n];
      float d = pred - labels[b * 24 + n];
      s += d * d;
    }
    atomicAdd(out, s * (1.0f / 6144.0f));
  }
}

extern "C" void kernel_launch(void* const* d_in, const int* in_sizes, int n_in,
                              void* d_out, int out_size, void* d_ws, size_t ws_size,
                              hipStream_t stream) {
  const float* features = (const float*)d_in[0];
  const float* labels   = (const float*)d_in[1];
  const float* W1 = (const float*)d_in[2];
  const float* b1 = (const float*)d_in[3];
  const float* W2 = (const float*)d_in[4];
  const float* b2 = (const float*)d_in[5];
  const float* Wd = (const float*)d_in[6];
  const float* bd = (const float*)d_in[7];

  char* ws = (char*)d_ws;
  unsigned short* zpad = (unsigned short*)(ws + OFF_ZPAD);
  unsigned int*   bar  = (unsigned int*)(ws + OFF_BAR);
  unsigned short* h1   = (unsigned short*)(ws + OFF_H1);
  unsigned short* h2   = (unsigned short*)(ws + OFF_H2);
  float*          b1p  = (float*)(ws + OFF_B1P);
  float*          b2p  = (float*)(ws + OFF_B2P);
  unsigned short* Xbf  = (unsigned short*)(ws + OFF_X);
  unsigned short* BP   = (unsigned short*)(ws + OFF_BP);
  float* out = (float*)d_out;

  init_zero<<<1026, 256, 0, stream>>>(out, (uint4*)ws, 262400L);
  feat2bf<<<5376, 256, 0, stream>>>(features, Xbf, 1376256L);
  bpack<<<3328, 256, 0, stream>>>(W1, W2, BP);
  bias_perm<<<32, 256, 0, stream>>>(b1, b2, b1p, b2p);

  // single persistent launch: 337 barrier-separated phases
  lstm_persist<<<256, 512, 0, stream>>>(Xbf, h1, h2, BP, b1p, b2p, zpad, bar);

  // final h2 is buffer (TT+1)&1 = 1
  head_loss<<<256, 64, 0, stream>>>(h2 + BBHH, Wd, bd, labels, out);
}